// Round 1
// baseline (2909.886 us; speedup 1.0000x reference)
//
#include <hip/hip_runtime.h>
#include <math.h>

#define LB __launch_bounds__(256)

static inline int cdiv(int a, int b){ return (a + b - 1) / b; }

// ---------------- CSR build ----------------

__global__ LB void zero_int(int* __restrict__ p, int n){
  int i = blockIdx.x * 256 + threadIdx.x;
  if (i < n) p[i] = 0;
}

__global__ LB void count_edges(const int* __restrict__ ei, const int* __restrict__ et,
                               int* __restrict__ cnt, int E, int R){
  int e = blockIdx.x * 256 + threadIdx.x;
  if (e >= E) return;
  int dst = ei[E + e];
  int ty  = et[e];
  atomicAdd(&cnt[dst * R + ty], 1);
}

__global__ LB void block_sum_k(const int* __restrict__ cnt, int* __restrict__ bsum, int NS){
  __shared__ int sh[256];
  int t = threadIdx.x;
  int base = blockIdx.x * 1024;
  int s = 0;
  for (int i = t; i < 1024; i += 256){ int g = base + i; if (g < NS) s += cnt[g]; }
  sh[t] = s; __syncthreads();
  for (int d = 128; d > 0; d >>= 1){ if (t < d) sh[t] += sh[t + d]; __syncthreads(); }
  if (t == 0) bsum[blockIdx.x] = sh[0];
}

// single block, nb <= 256 (NS <= 262144)
__global__ LB void scan_bsum_k(int* __restrict__ bsum, int nb){
  __shared__ int sh[256];
  int t = threadIdx.x;
  int v = (t < nb) ? bsum[t] : 0;
  sh[t] = v; __syncthreads();
  for (int d = 1; d < 256; d <<= 1){
    int add = (t >= d) ? sh[t - d] : 0;
    __syncthreads();
    sh[t] += add;
    __syncthreads();
  }
  if (t < nb) bsum[t] = sh[t] - v;  // exclusive
}

__global__ LB void scan_scatter_k(const int* __restrict__ cnt, const int* __restrict__ bsum,
                                  int* __restrict__ off, int* __restrict__ cursor,
                                  float* __restrict__ degInv, int NS){
  __shared__ int sh[256];
  int t = threadIdx.x;
  int base = blockIdx.x * 1024 + t * 4;
  int v[4];
  #pragma unroll
  for (int j = 0; j < 4; ++j){ int g = base + j; v[j] = (g < NS) ? cnt[g] : 0; }
  int tsum = v[0] + v[1] + v[2] + v[3];
  sh[t] = tsum; __syncthreads();
  for (int d = 1; d < 256; d <<= 1){
    int add = (t >= d) ? sh[t - d] : 0;
    __syncthreads();
    sh[t] += add;
    __syncthreads();
  }
  int o = bsum[blockIdx.x] + sh[t] - tsum;  // exclusive prefix for this thread's 4 elems
  #pragma unroll
  for (int j = 0; j < 4; ++j){
    int g = base + j;
    if (g < NS){
      off[g] = o;
      cursor[g] = o;
      degInv[g] = 1.0f / (float)(v[j] > 0 ? v[j] : 1);
      o += v[j];
      if (g == NS - 1) off[NS] = o;
    }
  }
}

__global__ LB void fill_edges(const int* __restrict__ ei, const int* __restrict__ et,
                              int* __restrict__ cursor, int* __restrict__ srcS, int E, int R){
  int e = blockIdx.x * 256 + threadIdx.x;
  if (e >= E) return;
  int src = ei[e];
  int dst = ei[E + e];
  int ty  = et[e];
  int pos = atomicAdd(&cursor[dst * R + ty], 1);
  srcS[pos] = src;
}

// ---------------- mean aggregation (D=128 hard-coded: float2 per lane over a wave64) ----------------

__global__ LB void agg_mean_k(const float* __restrict__ X, const int* __restrict__ srcS,
                              const int* __restrict__ off, const float* __restrict__ degInv,
                              float* __restrict__ mean, int NS){
  int w = (int)(((size_t)blockIdx.x * blockDim.x + threadIdx.x) >> 6);  // one wave per segment
  int lane = threadIdx.x & 63;
  if (w >= NS) return;
  int s0 = off[w], s1 = off[w + 1];
  float ax = 0.f, ay = 0.f;
  for (int i = s0; i < s1; ++i){
    int src = srcS[i];
    const float2 v = *(const float2*)(X + (size_t)src * 128 + lane * 2);
    ax += v.x; ay += v.y;
  }
  float di = degInv[w];
  float2* o = (float2*)(mean + (size_t)w * 128);
  o[lane] = make_float2(ax * di, ay * di);
}

// ---------------- generic fp32 tiled GEMM: C = op(A@B [+bias] [+C]) ----------------

template<int BN, bool LRELU, bool BIAS, bool ACCUM>
__global__ LB void gemm_f32(const float* __restrict__ A, int lda,
                            const float* __restrict__ B, int ldb,
                            float* __restrict__ C, int ldc,
                            const float* __restrict__ bias,
                            int M, int Nc, int K){
  constexpr int BM = 64, BK = 32;
  constexpr int TM = 4, TN = BN / 16;
  __shared__ float As[BM][BK + 1];
  __shared__ float Bs[BK][BN + 1];
  const int t = threadIdx.x;
  const int tx = t & 15, ty = t >> 4;
  const int row0 = blockIdx.x * BM;
  const int col0 = blockIdx.y * BN;
  float acc[TM][TN];
  #pragma unroll
  for (int i = 0; i < TM; ++i)
    #pragma unroll
    for (int j = 0; j < TN; ++j) acc[i][j] = 0.f;

  for (int k0 = 0; k0 < K; k0 += BK){
    for (int i = t; i < BM * BK; i += 256){
      int r = i >> 5, c = i & 31;
      int gr = row0 + r, gc = k0 + c;
      As[r][c] = (gr < M && gc < K) ? A[(size_t)gr * lda + gc] : 0.f;
    }
    for (int i = t; i < BK * BN; i += 256){
      int r = i / BN, c = i % BN;
      int gr = k0 + r, gc = col0 + c;
      Bs[r][c] = (gr < K && gc < Nc) ? B[(size_t)gr * ldb + gc] : 0.f;
    }
    __syncthreads();
    #pragma unroll
    for (int kk = 0; kk < BK; ++kk){
      float a[TM], b[TN];
      #pragma unroll
      for (int i = 0; i < TM; ++i) a[i] = As[ty * TM + i][kk];
      #pragma unroll
      for (int j = 0; j < TN; ++j) b[j] = Bs[kk][tx * TN + j];
      #pragma unroll
      for (int i = 0; i < TM; ++i)
        #pragma unroll
        for (int j = 0; j < TN; ++j)
          acc[i][j] = fmaf(a[i], b[j], acc[i][j]);
    }
    __syncthreads();
  }

  #pragma unroll
  for (int i = 0; i < TM; ++i){
    int gr = row0 + ty * TM + i;
    if (gr >= M) continue;
    #pragma unroll
    for (int j = 0; j < TN; ++j){
      int gc = col0 + tx * TN + j;
      if (gc >= Nc) continue;
      float v = acc[i][j];
      if (BIAS) v += bias[gc];
      if (ACCUM) v += C[(size_t)gr * ldc + gc];
      if (LRELU) v = (v >= 0.f) ? v : 0.01f * v;
      C[(size_t)gr * ldc + gc] = v;
    }
  }
}

// ---------------- head: softmax(H @ W_o2 + b_o2), D=128, 2 classes ----------------

__global__ LB void head_softmax(const float* __restrict__ H, const float* __restrict__ Wo2,
                                const float* __restrict__ bo2, float* __restrict__ out, int Nn){
  int gtid = blockIdx.x * 256 + threadIdx.x;
  int node = gtid >> 5;          // 32 lanes per node (half-wave)
  int lane = gtid & 31;
  if (node >= Nn) return;
  float l0 = 0.f, l1 = 0.f;
  #pragma unroll
  for (int kk = 0; kk < 4; ++kk){
    int k = lane + kk * 32;
    float h = H[(size_t)node * 128 + k];
    l0 = fmaf(h, Wo2[k * 2 + 0], l0);
    l1 = fmaf(h, Wo2[k * 2 + 1], l1);
  }
  #pragma unroll
  for (int m = 16; m >= 1; m >>= 1){
    l0 += __shfl_xor(l0, m, 64);
    l1 += __shfl_xor(l1, m, 64);
  }
  if (lane == 0){
    l0 += bo2[0]; l1 += bo2[1];
    float mx = fmaxf(l0, l1);
    float e0 = __expf(l0 - mx), e1 = __expf(l1 - mx);
    float inv = 1.f / (e0 + e1);
    out[(size_t)node * 2 + 0] = e0 * inv;
    out[(size_t)node * 2 + 1] = e1 * inv;
  }
}

// ---------------- launch ----------------

extern "C" void kernel_launch(void* const* d_in, const int* in_sizes, int n_in,
                              void* d_out, int out_size, void* d_ws, size_t ws_size,
                              hipStream_t stream) {
  const float* des    = (const float*)d_in[0];
  const float* tweet  = (const float*)d_in[1];
  const float* prop   = (const float*)d_in[2];
  const int*   ei     = (const int*)d_in[3];
  const int*   et     = (const int*)d_in[4];
  const float* W_des  = (const float*)d_in[5];
  const float* b_des  = (const float*)d_in[6];
  const float* W_tw   = (const float*)d_in[7];
  const float* b_tw   = (const float*)d_in[8];
  const float* W_pr   = (const float*)d_in[9];
  const float* b_pr   = (const float*)d_in[10];
  const float* W_in   = (const float*)d_in[11];
  const float* b_in   = (const float*)d_in[12];
  const float* W_rel  = (const float*)d_in[13];
  const float* W_root = (const float*)d_in[14];
  const float* b_rg   = (const float*)d_in[15];
  const float* W_o1   = (const float*)d_in[16];
  const float* b_o1   = (const float*)d_in[17];
  const float* W_o2   = (const float*)d_in[18];
  const float* b_o2   = (const float*)d_in[19];

  const int Nn = in_sizes[0] / 768;         // 100000
  const int E  = in_sizes[4];               // 3200000
  const int q  = in_sizes[6];               // 32
  const int D  = in_sizes[12];              // 128
  const int R  = in_sizes[13] / (D * D);    // 2
  const int NS = Nn * R;
  const int K3 = 3 * q;                     // 96

  // workspace carve (256B aligned)
  char* p = (char*)d_ws;
  auto carve = [&](size_t bytes) -> void* {
    void* r = (void*)p;
    p += (bytes + 255) & ~(size_t)255;
    return r;
  };
  int*   cnt     = (int*)  carve((size_t)NS * 4);
  int*   off     = (int*)  carve((size_t)(NS + 1) * 4);
  int*   cursor  = (int*)  carve((size_t)NS * 4);
  float* degInv  = (float*)carve((size_t)NS * 4);
  int*   bsum    = (int*)  carve(4096 * 4);
  int*   srcS    = (int*)  carve((size_t)E * 4);
  float* bufA    = (float*)carve((size_t)Nn * D * 4);
  float* bufB    = (float*)carve((size_t)Nn * D * 4);
  float* mean    = (float*)carve((size_t)Nn * R * D * 4);
  float* dtp     = mean;                    // N x 96 overlays mean (dead before agg)

  const int NB1 = cdiv(NS, 1024);

  // ---- CSR build (once; shared by both RGCN layers) ----
  zero_int<<<cdiv(NS, 256), 256, 0, stream>>>(cnt, NS);
  count_edges<<<cdiv(E, 256), 256, 0, stream>>>(ei, et, cnt, E, R);
  block_sum_k<<<NB1, 256, 0, stream>>>(cnt, bsum, NS);
  scan_bsum_k<<<1, 256, 0, stream>>>(bsum, NB1);
  scan_scatter_k<<<NB1, 256, 0, stream>>>(cnt, bsum, off, cursor, degInv, NS);
  fill_edges<<<cdiv(E, 256), 256, 0, stream>>>(ei, et, cursor, srcS, E, R);

  // ---- encoders: dtp[:,0:32]=lrelu(des@W_des+b), [:,32:64]=tweet, [:,64:96]=prop ----
  {
    dim3 g(cdiv(Nn, 64), cdiv(q, 32));
    gemm_f32<32, true, true, false><<<g, 256, 0, stream>>>(des,   768, W_des, q, dtp + 0,    K3, b_des, Nn, q, 768);
    gemm_f32<32, true, true, false><<<g, 256, 0, stream>>>(tweet, 768, W_tw,  q, dtp + q,    K3, b_tw,  Nn, q, 768);
    gemm_f32<32, true, true, false><<<g, 256, 0, stream>>>(prop,   14, W_pr,  q, dtp + 2*q,  K3, b_pr,  Nn, q, 14);
  }
  // ---- x = lrelu(dtp @ W_in + b_in) -> bufA ----
  {
    dim3 g(cdiv(Nn, 64), cdiv(D, 64));
    gemm_f32<64, true, true, false><<<g, 256, 0, stream>>>(dtp, K3, W_in, D, bufA, D, b_in, Nn, D, K3);
  }

  dim3 gD(cdiv(Nn, 64), cdiv(D, 64));
  int aggGrid = cdiv(NS * 64, 256);

  // ---- RGCN layer 1: bufA -> bufB ----
  agg_mean_k<<<aggGrid, 256, 0, stream>>>(bufA, srcS, off, degInv, mean, NS);
  gemm_f32<64, false, true, false><<<gD, 256, 0, stream>>>(bufA, D, W_root, D, bufB, D, b_rg, Nn, D, D);
  gemm_f32<64, false, false, true><<<gD, 256, 0, stream>>>(mean, R * D, W_rel, D, bufB, D, nullptr, Nn, D, R * D);

  // ---- RGCN layer 2: bufB -> bufA ----
  agg_mean_k<<<aggGrid, 256, 0, stream>>>(bufB, srcS, off, degInv, mean, NS);
  gemm_f32<64, false, true, false><<<gD, 256, 0, stream>>>(bufB, D, W_root, D, bufA, D, b_rg, Nn, D, D);
  gemm_f32<64, false, false, true><<<gD, 256, 0, stream>>>(mean, R * D, W_rel, D, bufA, D, nullptr, Nn, D, R * D);

  // ---- head: bufB = lrelu(bufA @ W_o1 + b_o1); out = softmax(bufB @ W_o2 + b_o2) ----
  gemm_f32<64, true, true, false><<<gD, 256, 0, stream>>>(bufA, D, W_o1, D, bufB, D, b_o1, Nn, D, D);
  head_softmax<<<cdiv(Nn * 32, 256), 256, 0, stream>>>(bufB, W_o2, b_o2, (float*)d_out, Nn);
}

// Round 2
// 1840.861 us; speedup vs baseline: 1.5807x; 1.5807x over previous
//
#include <hip/hip_runtime.h>
#include <math.h>

typedef __bf16 bf16;
typedef bf16  v8bf __attribute__((ext_vector_type(8)));
typedef float v4f  __attribute__((ext_vector_type(4)));

#define LB __launch_bounds__(256)

static inline int cdiv(int a, int b){ return (a + b - 1) / b; }

// ---------------- CSR build ----------------

__global__ LB void zero_int(int* __restrict__ p, int n){
  int i = blockIdx.x * 256 + threadIdx.x;
  if (i < n) p[i] = 0;
}

__global__ LB void count_edges(const int* __restrict__ ei, const int* __restrict__ et,
                               int* __restrict__ cnt, int E, int R){
  int e = blockIdx.x * 256 + threadIdx.x;
  if (e >= E) return;
  int dst = ei[E + e];
  int ty  = et[e];
  atomicAdd(&cnt[dst * R + ty], 1);
}

__global__ LB void block_sum_k(const int* __restrict__ cnt, int* __restrict__ bsum, int NS){
  __shared__ int sh[256];
  int t = threadIdx.x;
  int base = blockIdx.x * 1024;
  int s = 0;
  for (int i = t; i < 1024; i += 256){ int g = base + i; if (g < NS) s += cnt[g]; }
  sh[t] = s; __syncthreads();
  for (int d = 128; d > 0; d >>= 1){ if (t < d) sh[t] += sh[t + d]; __syncthreads(); }
  if (t == 0) bsum[blockIdx.x] = sh[0];
}

// single block, nb <= 256 (NS <= 262144)
__global__ LB void scan_bsum_k(int* __restrict__ bsum, int nb){
  __shared__ int sh[256];
  int t = threadIdx.x;
  int v = (t < nb) ? bsum[t] : 0;
  sh[t] = v; __syncthreads();
  for (int d = 1; d < 256; d <<= 1){
    int add = (t >= d) ? sh[t - d] : 0;
    __syncthreads();
    sh[t] += add;
    __syncthreads();
  }
  if (t < nb) bsum[t] = sh[t] - v;  // exclusive
}

__global__ LB void scan_scatter_k(const int* __restrict__ cnt, const int* __restrict__ bsum,
                                  int* __restrict__ off, int* __restrict__ cursor,
                                  float* __restrict__ degInv, int NS){
  __shared__ int sh[256];
  int t = threadIdx.x;
  int base = blockIdx.x * 1024 + t * 4;
  int v[4];
  #pragma unroll
  for (int j = 0; j < 4; ++j){ int g = base + j; v[j] = (g < NS) ? cnt[g] : 0; }
  int tsum = v[0] + v[1] + v[2] + v[3];
  sh[t] = tsum; __syncthreads();
  for (int d = 1; d < 256; d <<= 1){
    int add = (t >= d) ? sh[t - d] : 0;
    __syncthreads();
    sh[t] += add;
    __syncthreads();
  }
  int o = bsum[blockIdx.x] + sh[t] - tsum;
  #pragma unroll
  for (int j = 0; j < 4; ++j){
    int g = base + j;
    if (g < NS){
      off[g] = o;
      cursor[g] = o;
      degInv[g] = 1.0f / (float)(v[j] > 0 ? v[j] : 1);
      o += v[j];
      if (g == NS - 1) off[NS] = o;
    }
  }
}

__global__ LB void fill_edges(const int* __restrict__ ei, const int* __restrict__ et,
                              int* __restrict__ cursor, int* __restrict__ srcS, int E, int R){
  int e = blockIdx.x * 256 + threadIdx.x;
  if (e >= E) return;
  int src = ei[e];
  int dst = ei[E + e];
  int ty  = et[e];
  int pos = atomicAdd(&cursor[dst * R + ty], 1);
  srcS[pos] = src;
}

// ---------------- mean aggregation (D=128: float2 per lane over a wave64) ----------------

__global__ LB void agg_mean_k(const float* __restrict__ X, const int* __restrict__ srcS,
                              const int* __restrict__ off, const float* __restrict__ degInv,
                              float* __restrict__ mean, int NS){
  int w = (int)(((size_t)blockIdx.x * blockDim.x + threadIdx.x) >> 6);  // one wave per segment
  int lane = threadIdx.x & 63;
  if (w >= NS) return;
  int s0 = off[w], s1 = off[w + 1];
  float ax = 0.f, ay = 0.f;
  for (int i = s0; i < s1; ++i){
    int src = srcS[i];
    const float2 v = *(const float2*)(X + (size_t)src * 128 + lane * 2);
    ax += v.x; ay += v.y;
  }
  float di = degInv[w];
  float2* o = (float2*)(mean + (size_t)w * 128);
  o[lane] = make_float2(ax * di, ay * di);
}

// ---------------- weight prep: fp32 [K][N] -> bf16 BT [N][KP] (zero-pad K->KP) ----------------

__global__ LB void prep_bt(const float* __restrict__ W, bf16* __restrict__ BT,
                           int K, int Nc, int KP){
  int idx = blockIdx.x * 256 + threadIdx.x;
  if (idx >= Nc * KP) return;
  int n = idx / KP, k = idx - n * KP;
  BT[idx] = (k < K) ? (bf16)W[(size_t)k * Nc + n] : (bf16)0.f;
}

// stacked [W_root ; W_rel_flat] -> BT [D][3D]
__global__ LB void prep_stack(const float* __restrict__ Wroot, const float* __restrict__ Wrel,
                              bf16* __restrict__ BT, int D){
  int KP = 3 * D;
  int idx = blockIdx.x * 256 + threadIdx.x;
  if (idx >= D * KP) return;
  int n = idx / KP, k = idx - n * KP;
  float v = (k < D) ? Wroot[(size_t)k * D + n] : Wrel[(size_t)(k - D) * D + n];
  BT[idx] = (bf16)v;
}

// ---------------- bf16 MFMA GEMM: C = op( [A|A2] @ B + bias ) ----------------
// A fp32 row-major (cast to bf16 at staging). B pre-transposed bf16 BT[n][KP].
// DUALA: k < KA from A (lda), k >= KA from A2 (lda2). KA % 32 == 0 required.

template<int BN, bool LRELU, bool DUALA>
__global__ LB void gemm_mfma(const float* __restrict__ A, int lda,
                             const float* __restrict__ A2, int lda2, int KA,
                             const bf16* __restrict__ BT, int KP,
                             float* __restrict__ C, int ldc,
                             const float* __restrict__ bias,
                             int M, int K){
  __shared__ __align__(16) bf16 As[64][40];   // pad 8 bf16 -> 2-way conflicts only (free)
  __shared__ __align__(16) bf16 Bs[BN][40];
  const int t = threadIdx.x;
  const int row0 = blockIdx.x * 64;
  const int col0 = blockIdx.y * BN;
  const int wv = t >> 6, ln = t & 63;
  const int mr = ln & 15, quad = ln >> 4;
  const int sr = t >> 2;          // staging row 0..63
  const int sc = (t & 3) * 8;     // staging col 0,8,16,24

  v4f acc[BN / 16];
  #pragma unroll
  for (int f = 0; f < BN / 16; ++f) acc[f] = (v4f)0.f;

  for (int k0 = 0; k0 < KP; k0 += 32){
    // ---- stage A (fp32 -> bf16) ----
    {
      int gr = row0 + sr;
      int gk = k0 + sc;
      const float* src;
      if (DUALA && k0 >= KA) src = A2 + (size_t)gr * lda2 + (gk - KA);
      else                   src = A  + (size_t)gr * lda  + gk;
      bf16 tmp[8];
      if (gr < M && gk + 8 <= K){
        float4 f0 = *(const float4*)src;
        float4 f1 = *(const float4*)(src + 4);
        tmp[0]=(bf16)f0.x; tmp[1]=(bf16)f0.y; tmp[2]=(bf16)f0.z; tmp[3]=(bf16)f0.w;
        tmp[4]=(bf16)f1.x; tmp[5]=(bf16)f1.y; tmp[6]=(bf16)f1.z; tmp[7]=(bf16)f1.w;
      } else {
        #pragma unroll
        for (int j = 0; j < 8; ++j)
          tmp[j] = (gr < M && gk + j < K) ? (bf16)src[j] : (bf16)0.f;
      }
      *(v8bf*)&As[sr][sc] = *(v8bf*)tmp;
    }
    // ---- stage B (already bf16, transposed) ----
    if (BN == 64 || t < 128){
      *(v8bf*)&Bs[sr][sc] = *(const v8bf*)&BT[(size_t)(col0 + sr) * KP + k0 + sc];
    }
    __syncthreads();
    // ---- MFMA ----
    v8bf a = *(v8bf*)&As[wv * 16 + mr][quad * 8];
    #pragma unroll
    for (int f = 0; f < BN / 16; ++f){
      v8bf b = *(v8bf*)&Bs[f * 16 + mr][quad * 8];
      acc[f] = __builtin_amdgcn_mfma_f32_16x16x32_bf16(a, b, acc[f], 0, 0, 0);
    }
    __syncthreads();
  }

  // ---- epilogue: D[row=quad*4+r][col=mr] per 16x16 frag ----
  #pragma unroll
  for (int f = 0; f < BN / 16; ++f){
    int gc = col0 + f * 16 + mr;
    float bv = bias[gc];
    #pragma unroll
    for (int r = 0; r < 4; ++r){
      int gr = row0 + wv * 16 + quad * 4 + r;
      if (gr < M){
        float v = acc[f][r] + bv;
        if (LRELU) v = (v >= 0.f) ? v : 0.01f * v;
        C[(size_t)gr * ldc + gc] = v;
      }
    }
  }
}

// ---------------- head: softmax(H @ W_o2 + b_o2), D=128, 2 classes ----------------

__global__ LB void head_softmax(const float* __restrict__ H, const float* __restrict__ Wo2,
                                const float* __restrict__ bo2, float* __restrict__ out, int Nn){
  int gtid = blockIdx.x * 256 + threadIdx.x;
  int node = gtid >> 5;          // 32 lanes per node
  int lane = gtid & 31;
  if (node >= Nn) return;
  float l0 = 0.f, l1 = 0.f;
  #pragma unroll
  for (int kk = 0; kk < 4; ++kk){
    int k = lane + kk * 32;
    float h = H[(size_t)node * 128 + k];
    l0 = fmaf(h, Wo2[k * 2 + 0], l0);
    l1 = fmaf(h, Wo2[k * 2 + 1], l1);
  }
  #pragma unroll
  for (int m = 16; m >= 1; m >>= 1){
    l0 += __shfl_xor(l0, m, 64);
    l1 += __shfl_xor(l1, m, 64);
  }
  if (lane == 0){
    l0 += bo2[0]; l1 += bo2[1];
    float mx = fmaxf(l0, l1);
    float e0 = __expf(l0 - mx), e1 = __expf(l1 - mx);
    float inv = 1.f / (e0 + e1);
    out[(size_t)node * 2 + 0] = e0 * inv;
    out[(size_t)node * 2 + 1] = e1 * inv;
  }
}

// ---------------- launch ----------------

extern "C" void kernel_launch(void* const* d_in, const int* in_sizes, int n_in,
                              void* d_out, int out_size, void* d_ws, size_t ws_size,
                              hipStream_t stream) {
  const float* des    = (const float*)d_in[0];
  const float* tweet  = (const float*)d_in[1];
  const float* prop   = (const float*)d_in[2];
  const int*   ei     = (const int*)d_in[3];
  const int*   et     = (const int*)d_in[4];
  const float* W_des  = (const float*)d_in[5];
  const float* b_des  = (const float*)d_in[6];
  const float* W_tw   = (const float*)d_in[7];
  const float* b_tw   = (const float*)d_in[8];
  const float* W_pr   = (const float*)d_in[9];
  const float* b_pr   = (const float*)d_in[10];
  const float* W_in   = (const float*)d_in[11];
  const float* b_in   = (const float*)d_in[12];
  const float* W_rel  = (const float*)d_in[13];
  const float* W_root = (const float*)d_in[14];
  const float* b_rg   = (const float*)d_in[15];
  const float* W_o1   = (const float*)d_in[16];
  const float* b_o1   = (const float*)d_in[17];
  const float* W_o2   = (const float*)d_in[18];
  const float* b_o2   = (const float*)d_in[19];

  const int Nn = in_sizes[0] / 768;         // 100000
  const int E  = in_sizes[4];               // 3200000
  const int q  = in_sizes[6];               // 32
  const int D  = in_sizes[12];              // 128
  const int R  = in_sizes[13] / (D * D);    // 2
  const int NS = Nn * R;
  const int K3 = 3 * q;                     // 96

  // workspace carve (256B aligned)
  char* p = (char*)d_ws;
  auto carve = [&](size_t bytes) -> void* {
    void* r = (void*)p;
    p += (bytes + 255) & ~(size_t)255;
    return r;
  };
  int*   cnt     = (int*)  carve((size_t)NS * 4);
  int*   off     = (int*)  carve((size_t)(NS + 1) * 4);
  int*   cursor  = (int*)  carve((size_t)NS * 4);
  float* degInv  = (float*)carve((size_t)NS * 4);
  int*   bsum    = (int*)  carve(4096 * 4);
  int*   srcS    = (int*)  carve((size_t)E * 4);
  float* bufA    = (float*)carve((size_t)Nn * D * 4);
  float* bufB    = (float*)carve((size_t)Nn * D * 4);
  float* mean    = (float*)carve((size_t)Nn * R * D * 4);
  float* dtp     = mean;                    // N x 96 overlays mean (dead before agg)
  bf16*  BT_des  = (bf16*) carve((size_t)q * 768 * 2);
  bf16*  BT_tw   = (bf16*) carve((size_t)q * 768 * 2);
  bf16*  BT_pr   = (bf16*) carve((size_t)q * 32 * 2);
  bf16*  BT_in   = (bf16*) carve((size_t)D * K3 * 2);
  bf16*  BT_st   = (bf16*) carve((size_t)D * 3 * D * 2);
  bf16*  BT_o1   = (bf16*) carve((size_t)D * D * 2);

  const int NB1 = cdiv(NS, 1024);

  // ---- CSR build (once; shared by both RGCN layers) ----
  zero_int<<<cdiv(NS, 256), 256, 0, stream>>>(cnt, NS);
  count_edges<<<cdiv(E, 256), 256, 0, stream>>>(ei, et, cnt, E, R);
  block_sum_k<<<NB1, 256, 0, stream>>>(cnt, bsum, NS);
  scan_bsum_k<<<1, 256, 0, stream>>>(bsum, NB1);
  scan_scatter_k<<<NB1, 256, 0, stream>>>(cnt, bsum, off, cursor, degInv, NS);
  fill_edges<<<cdiv(E, 256), 256, 0, stream>>>(ei, et, cursor, srcS, E, R);

  // ---- weight prep (bf16, transposed, K zero-padded to mult of 32) ----
  prep_bt<<<cdiv(q * 768, 256), 256, 0, stream>>>(W_des, BT_des, 768, q, 768);
  prep_bt<<<cdiv(q * 768, 256), 256, 0, stream>>>(W_tw,  BT_tw,  768, q, 768);
  prep_bt<<<cdiv(q * 32, 256), 256, 0, stream>>>(W_pr,  BT_pr,  14,  q, 32);
  prep_bt<<<cdiv(D * K3, 256), 256, 0, stream>>>(W_in,  BT_in,  K3,  D, K3);
  prep_stack<<<cdiv(D * 3 * D, 256), 256, 0, stream>>>(W_root, W_rel, BT_st, D);
  prep_bt<<<cdiv(D * D, 256), 256, 0, stream>>>(W_o1,  BT_o1,  D,   D, D);

  const int gx = cdiv(Nn, 64);

  // ---- encoders -> dtp[:, 0:32 | 32:64 | 64:96] ----
  gemm_mfma<32, true, false><<<dim3(gx, 1), 256, 0, stream>>>(
      des, 768, nullptr, 0, 0, BT_des, 768, dtp + 0, K3, b_des, Nn, 768);
  gemm_mfma<32, true, false><<<dim3(gx, 1), 256, 0, stream>>>(
      tweet, 768, nullptr, 0, 0, BT_tw, 768, dtp + q, K3, b_tw, Nn, 768);
  gemm_mfma<32, true, false><<<dim3(gx, 1), 256, 0, stream>>>(
      prop, 14, nullptr, 0, 0, BT_pr, 32, dtp + 2 * q, K3, b_pr, Nn, 14);

  // ---- x = lrelu(dtp @ W_in + b_in) -> bufA ----
  gemm_mfma<64, true, false><<<dim3(gx, 2), 256, 0, stream>>>(
      dtp, K3, nullptr, 0, 0, BT_in, K3, bufA, D, b_in, Nn, K3);

  const int aggGrid = cdiv(NS * 64, 256);

  // ---- RGCN layer 1: bufA -> bufB (fused root+rel, K=384) ----
  agg_mean_k<<<aggGrid, 256, 0, stream>>>(bufA, srcS, off, degInv, mean, NS);
  gemm_mfma<64, false, true><<<dim3(gx, 2), 256, 0, stream>>>(
      bufA, D, mean, R * D, D, BT_st, 3 * D, bufB, D, b_rg, Nn, 3 * D);

  // ---- RGCN layer 2: bufB -> bufA ----
  agg_mean_k<<<aggGrid, 256, 0, stream>>>(bufB, srcS, off, degInv, mean, NS);
  gemm_mfma<64, false, true><<<dim3(gx, 2), 256, 0, stream>>>(
      bufB, D, mean, R * D, D, BT_st, 3 * D, bufA, D, b_rg, Nn, 3 * D);

  // ---- head ----
  gemm_mfma<64, true, false><<<dim3(gx, 2), 256, 0, stream>>>(
      bufA, D, nullptr, 0, 0, BT_o1, D, bufB, D, b_o1, Nn, D);
  head_softmax<<<cdiv(Nn * 32, 256), 256, 0, stream>>>(bufB, W_o2, b_o2, (float*)d_out, Nn);
}